// Round 2
// baseline (1203.030 us; speedup 1.0000x reference)
//
#include <hip/hip_runtime.h>
#include <stdint.h>

// Problem constants (B=2, S=8192, H=1024, F=2048, E=8, K=2)
#define T_TOK 16384
#define H_DIM 1024
#define F_DIM 2048
#define E_NUM 8
#define N_SLOT 32768           // T_TOK * 2
#define CAP 5120               // ceil(1.25 * 32768 / 8), divisible by 256
#define EGROUP 3               // experts per pipeline group (hbuf sized for this)

typedef __attribute__((ext_vector_type(8))) short bf16x8;   // 8 bf16 = 4 VGPRs
typedef __attribute__((ext_vector_type(4))) float f32x4;    // MFMA accumulator

__device__ __forceinline__ unsigned short f2bf(float f) {
  unsigned int x = __float_as_uint(f);
  x += 0x7fffu + ((x >> 16) & 1u);       // round-to-nearest-even
  return (unsigned short)(x >> 16);
}
__device__ __forceinline__ float bf2f(unsigned short u) {
  return __uint_as_float(((unsigned int)u) << 16);
}

// raw workgroup barrier, NO vmcnt/lgkm drain; empty memory-clobber asm pins
// compiler-level ordering of LDS ops around it.
__device__ __forceinline__ void bar_sync() {
  asm volatile("" ::: "memory");
  __builtin_amdgcn_s_barrier();
  asm volatile("" ::: "memory");
}

// ---------------- fallback: ws too small -> zero out, report ws_size in aux ----------------
__global__ void fallback_kernel(float* out, int out_size, float wsval) {
  size_t i = (size_t)blockIdx.x * blockDim.x + threadIdx.x;
  size_t stride = (size_t)gridDim.x * blockDim.x;
  for (size_t k = i; k < (size_t)out_size; k += stride)
    out[k] = (k == (size_t)out_size - 1) ? wsval : 0.f;
}

// ---------------- zero control block ----------------
__global__ void zero_ctrl_kernel(float* imp, int* counts, int* order) {
  int i = threadIdx.x;
  if (i < E_NUM) { imp[i] = 0.f; counts[i] = 0; order[i] = 0; }
}

// ---- transpose + f32->bf16 convert: src [E][R][C] f32 -> dst [E][C][R] bf16 ----
__global__ __launch_bounds__(256) void transpose_kernel(
    const float* __restrict__ src, unsigned short* __restrict__ dst, int R, int C) {
  __shared__ float tile[32][33];
  int e = blockIdx.z;
  int c0 = blockIdx.x * 32, r0 = blockIdx.y * 32;
  int tx = threadIdx.x & 31, ty = threadIdx.x >> 5;
  const float* s = src + ((size_t)e * R + r0) * C + c0;
#pragma unroll
  for (int k = 0; k < 4; ++k) tile[ty + 8 * k][tx] = s[(size_t)(ty + 8 * k) * C + tx];
  __syncthreads();
  unsigned short* d = dst + ((size_t)e * C + c0) * R + r0;
#pragma unroll
  for (int k = 0; k < 4; ++k) d[(size_t)(ty + 8 * k) * R + tx] = f2bf(tile[tx][ty + 8 * k]);
}

// ---------------- router: fp64 logits/softmax/top-2 (tie-flip safety), importance/load ----------------
__global__ __launch_bounds__(256) void router_kernel(
    const float* __restrict__ x, const float* __restrict__ Wr,
    int* __restrict__ top_idx, float* __restrict__ top_w,
    float* __restrict__ importance, int* __restrict__ counts) {
  __shared__ float s_imp[E_NUM];
  __shared__ int s_cnt[E_NUM];
  int tid = threadIdx.x;
  if (tid < E_NUM) { s_imp[tid] = 0.f; s_cnt[tid] = 0; }
  __syncthreads();
  int wave = tid >> 6, lane = tid & 63;
  int t = blockIdx.x * 4 + wave;           // one wave per token
  double acc[E_NUM];
#pragma unroll
  for (int e = 0; e < E_NUM; ++e) acc[e] = 0.0;
  const float* xt = x + (size_t)t * H_DIM;
#pragma unroll 2
  for (int i = 0; i < H_DIM / 64; ++i) {
    int h = i * 64 + lane;
    double xv = (double)xt[h];
    const float4* wr = (const float4*)(Wr + h * E_NUM);
    float4 w0 = wr[0], w1 = wr[1];
    acc[0] += xv * (double)w0.x; acc[1] += xv * (double)w0.y;
    acc[2] += xv * (double)w0.z; acc[3] += xv * (double)w0.w;
    acc[4] += xv * (double)w1.x; acc[5] += xv * (double)w1.y;
    acc[6] += xv * (double)w1.z; acc[7] += xv * (double)w1.w;
  }
#pragma unroll
  for (int e = 0; e < E_NUM; ++e)
    for (int off = 32; off; off >>= 1) acc[e] += __shfl_xor(acc[e], off, 64);
  if (lane == 0) {
    double mx = acc[0];
#pragma unroll
    for (int e = 1; e < E_NUM; ++e) mx = acc[e] > mx ? acc[e] : mx;
    double p[E_NUM]; double s = 0.0;
#pragma unroll
    for (int e = 0; e < E_NUM; ++e) { p[e] = exp(acc[e] - mx); s += p[e]; }
    double inv = 1.0 / s;
    // top-2 (ties -> lower index, matching jax.lax.top_k)
    int i0 = 0; double p0 = p[0];
#pragma unroll
    for (int e = 1; e < E_NUM; ++e) if (p[e] > p0) { p0 = p[e]; i0 = e; }
    int i1 = -1; double p1 = -1.0;
#pragma unroll
    for (int e = 0; e < E_NUM; ++e) if (e != i0 && p[e] > p1) { p1 = p[e]; i1 = e; }
    double wsum = p0 + p1;
    top_idx[2 * t] = i0; top_idx[2 * t + 1] = i1;
    top_w[2 * t] = (float)(p0 / wsum);
    top_w[2 * t + 1] = (float)(p1 / wsum);
#pragma unroll
    for (int e = 0; e < E_NUM; ++e) atomicAdd(&s_imp[e], (float)(p[e] * inv));
    atomicAdd(&s_cnt[i0], 1); atomicAdd(&s_cnt[i1], 1);
  }
  __syncthreads();
  if (tid < E_NUM) { atomicAdd(&importance[tid], s_imp[tid]); atomicAdd(&counts[tid], s_cnt[tid]); }
}

// ---------------- aux loss ----------------
__global__ void aux_kernel(const float* __restrict__ importance, const int* __restrict__ counts,
                           float* __restrict__ aux_out) {
  if (threadIdx.x == 0) {
    float s = 0.f;
    for (int e = 0; e < E_NUM; ++e) s += importance[e] * (float)counts[e];
    *aux_out = (float)E_NUM * s / (float)N_SLOT;
  }
}

// ---------------- per-slot position assignment ----------------
__global__ __launch_bounds__(256) void assign_pos_kernel(
    const int* __restrict__ top_idx, const float* __restrict__ top_w,
    const int* __restrict__ counts, int* __restrict__ order, int* __restrict__ pos) {
  int i = blockIdx.x * 256 + threadIdx.x;
  if (i >= N_SLOT) return;
  int e = top_idx[i];
  int c = counts[e];
  if (c <= CAP) {
    pos[i] = atomicAdd(&order[e], 1);
  } else {
    float p = top_w[i]; int r = 0;
    for (int j = 0; j < N_SLOT; ++j) {
      if (top_idx[j] == e) {
        float q = top_w[j];
        r += (q > p) || (q == p && j < i);
      }
    }
    pos[i] = (r < CAP) ? r : -1;   // dropped
  }
}

// ---------------- dispatch: x[token] -> x_disp[e][pos] (bf16) ----------------
__global__ __launch_bounds__(256) void dispatch_kernel(
    const float* __restrict__ x, const int* __restrict__ top_idx,
    const int* __restrict__ pos, unsigned short* __restrict__ xd) {
  int s = blockIdx.x;
  int p = pos[s];
  if (p < 0) return;
  int e = top_idx[s];
  int t = s >> 1;
  float4 v = ((const float4*)(x + (size_t)t * H_DIM))[threadIdx.x];
  unsigned short* d = xd + ((size_t)e * CAP + p) * H_DIM + threadIdx.x * 4;
  *(ushort4*)d = make_ushort4(f2bf(v.x), f2bf(v.y), f2bf(v.z), f2bf(v.w));
}

// ---------------- GEMM staging: ROWSx32 bf16 tile via global_load_lds ----------------
// LDS row m chunk q (16B chunks, 4/row) holds global chunk q ^ ((m>>1)&3): breaks the
// 64B-row same-bank pattern for ds_read_b128 fragment reads (measured 0 conflicts).
// LDS dest linear (wave-uniform base + lane*16B contract); global SOURCE pre-swizzled.
template<int NCHUNK>
__device__ __forceinline__ void stage32(const unsigned short* __restrict__ g,
                                        unsigned short* s, int ldg, int tid) {
#pragma unroll
  for (int j = 0; j < NCHUNK / 512; ++j) {
    int c = j * 512 + tid;
    int m = c >> 2;
    int kc = (c & 3) ^ ((m >> 1) & 3);
    const unsigned short* gp = g + (size_t)m * ldg + kc * 8;
    __builtin_amdgcn_global_load_lds((const __attribute__((address_space(1))) void*)gp,
                                     (__attribute__((address_space(3))) void*)(s + (size_t)c * 8),
                                     16, 0, 0);
  }
}
// NCHUNK=512 case (B tiles of gateup): one load, no loop
__device__ __forceinline__ void stage32_512(const unsigned short* __restrict__ g,
                                            unsigned short* s, int ldg, int tid) {
  int m = tid >> 2;
  int kc = (tid & 3) ^ ((m >> 1) & 3);
  const unsigned short* gp = g + (size_t)m * ldg + kc * 8;
  __builtin_amdgcn_global_load_lds((const __attribute__((address_space(1))) void*)gp,
                                   (__attribute__((address_space(3))) void*)(s + (size_t)tid * 8),
                                   16, 0, 0);
}

// bijective XCD-aware remap of the xy-plane block index (m204 formula)
__device__ __forceinline__ int xcd_swizzle(int id, int nwg) {
  int q = nwg >> 3, r = nwg & 7;
  int xcd = id & 7, sub = id >> 3;
  return (xcd < r ? xcd * (q + 1) : r * (q + 1) + (xcd - r) * q) + sub;
}

// ---------------- fused gate/up GEMM + SiLU: h = silu(X@Wg) * (X@Wu) ----------------
// 256x128 tile, BK=32, 8 waves (4M x 2N, per-wave 64x64), QUAD-buffered LDS ring
// (4 x 32 KB = 128 KB). Iteration t issues tile t+3's 4 loads -> vmcnt(12) (tile t
// landed; 12 loads across 3 future tiles stay in flight over both barriers) ->
// barrier -> MFMA (setprio-wrapped) -> barrier. Depth-3 prefetch (~960 cyc) covers
// HBM latency; only the peeled tail ever drains vmcnt.
__global__ __launch_bounds__(512, 2) void gateup_kernel(
    const unsigned short* __restrict__ xd, const unsigned short* __restrict__ wgT,
    const unsigned short* __restrict__ wuT, const int* __restrict__ counts,
    unsigned short* __restrict__ hbuf, int e0) {
  int ez = blockIdx.z;                    // local expert index within group
  int e = e0 + ez;                        // global expert
  int rows = counts[e]; rows = rows > CAP ? CAP : rows;
  // T1: XCD-aware swizzle of (bx,by) so neighbor tiles (sharing A/B panels) co-locate per XCD L2
  int nwg = gridDim.x * gridDim.y;        // 320 (%8==0 -> bijective)
  int swz = xcd_swizzle(blockIdx.y * gridDim.x + blockIdx.x, nwg);
  int bx = swz % gridDim.x, by = swz / gridDim.x;
  int tm = by * 256;
  if (tm >= rows) return;                 // block-uniform early exit (before any barrier)
  int tn = bx * 128;
  __shared__ __align__(16) unsigned short sA[4][256 * 32];   // 4 x 16 KB
  __shared__ __align__(16) unsigned short sBg[4][128 * 32];  // 4 x 8 KB
  __shared__ __align__(16) unsigned short sBu[4][128 * 32];  // 4 x 8 KB
  int tid = threadIdx.x;
  int lane = tid & 63, wave = tid >> 6;
  int quad = lane >> 4, lr = lane & 15;
  int wm = (wave >> 1) * 64, wn = (wave & 1) * 64;
  const unsigned short* A  = xd  + ((size_t)e * CAP + tm) * H_DIM;
  const unsigned short* Bg = wgT + ((size_t)e * F_DIM + tn) * H_DIM;
  const unsigned short* Bu = wuT + ((size_t)e * F_DIM + tn) * H_DIM;
  f32x4 accg[4][4], accu[4][4];
  f32x4 zero = {0.f, 0.f, 0.f, 0.f};
#pragma unroll
  for (int i = 0; i < 4; ++i)
#pragma unroll
    for (int j = 0; j < 4; ++j) { accg[i][j] = zero; accu[i][j] = zero; }

  auto STAGE = [&](int kt, int b) {
    stage32<1024>(A + kt * 32, sA[b], H_DIM, tid);
    stage32_512(Bg + kt * 32, sBg[b], H_DIM, tid);
    stage32_512(Bu + kt * 32, sBu[b], H_DIM, tid);
  };
  auto COMP = [&](int b) {
    const unsigned short* a = sA[b];
    const unsigned short* bg = sBg[b];
    const unsigned short* bu = sBu[b];
    bf16x8 af[4], gf[4], uf[4];
#pragma unroll
    for (int i = 0; i < 4; ++i) {
      int m = wm + i * 16 + lr;
      af[i] = *(const bf16x8*)&a[m * 32 + ((quad ^ ((m >> 1) & 3)) << 3)];
    }
#pragma unroll
    for (int j = 0; j < 4; ++j) {
      int n = wn + j * 16 + lr;
      int off = n * 32 + ((quad ^ ((n >> 1) & 3)) << 3);
      gf[j] = *(const bf16x8*)&bg[off];
      uf[j] = *(const bf16x8*)&bu[off];
    }
    __builtin_amdgcn_s_setprio(1);
#pragma unroll
    for (int i = 0; i < 4; ++i)
#pragma unroll
      for (int j = 0; j < 4; ++j) {
        accg[i][j] = __builtin_amdgcn_mfma_f32_16x16x32_bf16(af[i], gf[j], accg[i][j], 0, 0, 0);
        accu[i][j] = __builtin_amdgcn_mfma_f32_16x16x32_bf16(af[i], uf[j], accu[i][j], 0, 0, 0);
      }
    __builtin_amdgcn_s_setprio(0);
  };

  // prologue: 3 tiles in flight (12 loads)
  STAGE(0, 0); STAGE(1, 1); STAGE(2, 2);
  const int NT = H_DIM / 32;  // 32
  for (int t = 0; t < NT - 3; ++t) {
    // ring slot (t+3)&3 was last read in COMP(t-1), sealed by its trailing barrier
    STAGE(t + 3, (t + 3) & 3);
    asm volatile("s_waitcnt vmcnt(12)" ::: "memory");  // tile t landed; t+1..t+3 in flight
    bar_sync();                                        // all waves' tile-t loads landed
    COMP(t & 3);
    bar_sync();                                        // reads done before next overwrite
  }
  asm volatile("s_waitcnt vmcnt(8)" ::: "memory"); bar_sync(); COMP((NT - 3) & 3);
  asm volatile("s_waitcnt vmcnt(4)" ::: "memory"); bar_sync(); COMP((NT - 2) & 3);
  asm volatile("s_waitcnt vmcnt(0)" ::: "memory"); bar_sync(); COMP((NT - 1) & 3);

  // epilogue: silu(g)*u -> bf16  (C/D layout: row = quad*4+r, col = lr)
  unsigned short* hp = hbuf + ((size_t)ez * CAP + tm) * F_DIM + tn;
#pragma unroll
  for (int i = 0; i < 4; ++i)
#pragma unroll
    for (int j = 0; j < 4; ++j)
#pragma unroll
      for (int r = 0; r < 4; ++r) {
        int m = wm + i * 16 + quad * 4 + r;
        int n = wn + j * 16 + lr;
        float g = accg[i][j][r], u = accu[i][j][r];
        float hv = (g / (1.f + __expf(-g))) * u;
        hp[(size_t)m * F_DIM + n] = f2bf(hv);
      }
}

// ---------------- down GEMM: y = h @ W2 ----------------
// 256x256 tile, BK=32, 8 waves (2M x 4N, per-wave 128x64), same quad-buffered ring.
__global__ __launch_bounds__(512, 2) void down_kernel(
    const unsigned short* __restrict__ hbuf, const unsigned short* __restrict__ w2T,
    const int* __restrict__ counts, unsigned short* __restrict__ ybuf, int e0) {
  int ez = blockIdx.z;
  int e = e0 + ez;
  int rows = counts[e]; rows = rows > CAP ? CAP : rows;
  int nwg = gridDim.x * gridDim.y;        // 80 (%8==0 -> bijective)
  int swz = xcd_swizzle(blockIdx.y * gridDim.x + blockIdx.x, nwg);
  int bx = swz % gridDim.x, by = swz / gridDim.x;
  int tm = by * 256;
  if (tm >= rows) return;
  int tn = bx * 256;
  __shared__ __align__(16) unsigned short sA[4][256 * 32];   // 4 x 16 KB
  __shared__ __align__(16) unsigned short sB[4][256 * 32];   // 4 x 16 KB
  int tid = threadIdx.x;
  int lane = tid & 63, wave = tid >> 6;
  int quad = lane >> 4, lr = lane & 15;
  int wm = (wave >> 2) * 128, wn = (wave & 3) * 64;
  const unsigned short* A = hbuf + ((size_t)ez * CAP + tm) * F_DIM;
  const unsigned short* B = w2T + ((size_t)e * H_DIM + tn) * F_DIM;
  f32x4 acc[8][4];
  f32x4 zero = {0.f, 0.f, 0.f, 0.f};
#pragma unroll
  for (int i = 0; i < 8; ++i)
#pragma unroll
    for (int j = 0; j < 4; ++j) acc[i][j] = zero;

  auto STAGE = [&](int kt, int b) {
    stage32<1024>(A + kt * 32, sA[b], F_DIM, tid);
    stage32<1024>(B + kt * 32, sB[b], F_DIM, tid);
  };
  auto COMP = [&](int bsel) {
    const unsigned short* a = sA[bsel];
    const unsigned short* b = sB[bsel];
    bf16x8 af[8], bf[4];
#pragma unroll
    for (int i = 0; i < 8; ++i) {
      int m = wm + i * 16 + lr;
      af[i] = *(const bf16x8*)&a[m * 32 + ((quad ^ ((m >> 1) & 3)) << 3)];
    }
#pragma unroll
    for (int j = 0; j < 4; ++j) {
      int n = wn + j * 16 + lr;
      bf[j] = *(const bf16x8*)&b[n * 32 + ((quad ^ ((n >> 1) & 3)) << 3)];
    }
    __builtin_amdgcn_s_setprio(1);
#pragma unroll
    for (int i = 0; i < 8; ++i)
#pragma unroll
      for (int j = 0; j < 4; ++j)
        acc[i][j] = __builtin_amdgcn_mfma_f32_16x16x32_bf16(af[i], bf[j], acc[i][j], 0, 0, 0);
    __builtin_amdgcn_s_setprio(0);
  };

  STAGE(0, 0); STAGE(1, 1); STAGE(2, 2);
  const int NT = F_DIM / 32;  // 64
  for (int t = 0; t < NT - 3; ++t) {
    STAGE(t + 3, (t + 3) & 3);
    asm volatile("s_waitcnt vmcnt(12)" ::: "memory");
    bar_sync();
    COMP(t & 3);
    bar_sync();
  }
  asm volatile("s_waitcnt vmcnt(8)" ::: "memory"); bar_sync(); COMP((NT - 3) & 3);
  asm volatile("s_waitcnt vmcnt(4)" ::: "memory"); bar_sync(); COMP((NT - 2) & 3);
  asm volatile("s_waitcnt vmcnt(0)" ::: "memory"); bar_sync(); COMP((NT - 1) & 3);

  unsigned short* yp = ybuf + ((size_t)e * CAP + tm) * H_DIM + tn;
#pragma unroll
  for (int i = 0; i < 8; ++i)
#pragma unroll
    for (int j = 0; j < 4; ++j)
#pragma unroll
      for (int r = 0; r < 4; ++r) {
        int m = wm + i * 16 + quad * 4 + r;
        int n = wn + j * 16 + lr;
        yp[(size_t)m * H_DIM + n] = f2bf(acc[i][j][r]);
      }
}

// ---------------- combine: out[t] = sum_k w_k * y[e_k][pos_k] ----------------
__global__ __launch_bounds__(256) void combine_kernel(
    const unsigned short* __restrict__ ybuf, const int* __restrict__ top_idx,
    const int* __restrict__ pos, const float* __restrict__ top_w,
    float* __restrict__ out) {
  int t = blockIdx.x;
  int i0 = 2 * t, i1 = 2 * t + 1;
  int e0 = top_idx[i0], e1 = top_idx[i1];
  int p0 = pos[i0], p1 = pos[i1];
  float w0 = (p0 >= 0) ? top_w[i0] : 0.f;
  float w1 = (p1 >= 0) ? top_w[i1] : 0.f;
  size_t o0 = ((size_t)e0 * CAP + (p0 < 0 ? 0 : p0)) * H_DIM + threadIdx.x * 4;
  size_t o1 = ((size_t)e1 * CAP + (p1 < 0 ? 0 : p1)) * H_DIM + threadIdx.x * 4;
  ushort4 a = *(const ushort4*)(ybuf + o0);
  ushort4 b = *(const ushort4*)(ybuf + o1);
  float4 o;
  o.x = w0 * bf2f(a.x) + w1 * bf2f(b.x);
  o.y = w0 * bf2f(a.y) + w1 * bf2f(b.y);
  o.z = w0 * bf2f(a.z) + w1 * bf2f(b.z);
  o.w = w0 * bf2f(a.w) + w1 * bf2f(b.w);
  *(float4*)(out + (size_t)t * H_DIM + threadIdx.x * 4) = o;
}

extern "C" void kernel_launch(void* const* d_in, const int* in_sizes, int n_in,
                              void* d_out, int out_size, void* d_ws, size_t ws_size,
                              hipStream_t stream) {
  const float* x  = (const float*)d_in[0];   // [2,8192,1024]
  const float* Wr = (const float*)d_in[1];   // [1024,8]
  const float* Wg = (const float*)d_in[2];   // [8,1024,2048]
  const float* Wu = (const float*)d_in[3];   // [8,1024,2048]
  const float* W2 = (const float*)d_in[4];   // [8,2048,1024]
  float* out = (float*)d_out;                // [16M out] + [1 aux]

  // ---- workspace layout (grouped hbuf; peak 248.0 MB, ws_size = 256 MiB) ----
  const size_t SZ_W  = (size_t)E_NUM * F_DIM * H_DIM * 2;    // 33.55 MB per transposed weight
  const size_t SZ_XD = (size_t)E_NUM * CAP * H_DIM * 2;      // 83.89 MB
  const size_t SZ_HG = (size_t)EGROUP * CAP * F_DIM * 2;     // 62.91 MB (3-expert hbuf)
  const size_t NEED  = 524288 + 3 * SZ_W + SZ_XD + SZ_HG;    // 247.99 MB

  if (ws_size < NEED) {
    fallback_kernel<<<4096, 256, 0, stream>>>(out, out_size, (float)ws_size);
    return;
  }

  char* w = (char*)d_ws;
  float* importance = (float*)(w + 0);
  int* counts       = (int*)(w + 64);
  int* order        = (int*)(w + 128);
  int* top_idx      = (int*)(w + 1024);
  int* pos          = (int*)(w + 1024 + 131072);
  float* top_w      = (float*)(w + 1024 + 2 * 131072);
  size_t off = 524288;
  unsigned short* wgT  = (unsigned short*)(w + off); off += SZ_W;
  unsigned short* wuT  = (unsigned short*)(w + off); off += SZ_W;
  unsigned short* w2T  = (unsigned short*)(w + off); off += SZ_W;
  unsigned short* xd   = (unsigned short*)(w + off); off += SZ_XD;
  unsigned short* hbuf = (unsigned short*)(w + off); off += SZ_HG;
  unsigned short* ybuf = xd;    // aliases xd: down(e) runs after gateup(e) consumed xd[e]

  zero_ctrl_kernel<<<1, 64, 0, stream>>>(importance, counts, order);
  // weight transposes (src [E][R][C] f32 -> dst [E][C][R] bf16)
  transpose_kernel<<<dim3(F_DIM / 32, H_DIM / 32, E_NUM), 256, 0, stream>>>(Wg, wgT, H_DIM, F_DIM);
  transpose_kernel<<<dim3(F_DIM / 32, H_DIM / 32, E_NUM), 256, 0, stream>>>(Wu, wuT, H_DIM, F_DIM);
  transpose_kernel<<<dim3(H_DIM / 32, F_DIM / 32, E_NUM), 256, 0, stream>>>(W2, w2T, F_DIM, H_DIM);
  router_kernel<<<T_TOK / 4, 256, 0, stream>>>(x, Wr, top_idx, top_w, importance, counts);
  aux_kernel<<<1, 64, 0, stream>>>(importance, counts, out + (out_size - 1));
  assign_pos_kernel<<<N_SLOT / 256, 256, 0, stream>>>(top_idx, top_w, counts, order, pos);
  dispatch_kernel<<<N_SLOT, 256, 0, stream>>>(x, top_idx, pos, xd);
  // expert groups: hbuf holds <= EGROUP experts at a time
  for (int e0 = 0; e0 < E_NUM; e0 += EGROUP) {
    int ne = (E_NUM - e0) < EGROUP ? (E_NUM - e0) : EGROUP;
    gateup_kernel<<<dim3(F_DIM / 128, CAP / 256, ne), 512, 0, stream>>>(xd, wgT, wuT, counts, hbuf, e0);
    down_kernel<<<dim3(H_DIM / 256, CAP / 256, ne), 512, 0, stream>>>(hbuf, w2T, counts, ybuf, e0);
  }
  combine_kernel<<<T_TOK, 256, 0, stream>>>(ybuf, top_idx, pos, top_w, out);
}

// Round 3
// 1099.674 us; speedup vs baseline: 1.0940x; 1.0940x over previous
//
#include <hip/hip_runtime.h>
#include <stdint.h>

// Problem constants (B=2, S=8192, H=1024, F=2048, E=8, K=2)
#define T_TOK 16384
#define H_DIM 1024
#define F_DIM 2048
#define E_NUM 8
#define N_SLOT 32768           // T_TOK * 2
#define CAP 5120               // ceil(1.25 * 32768 / 8), divisible by 256
#define EGROUP 3               // experts per pipeline group (hbuf sized for this)

typedef __attribute__((ext_vector_type(8))) short bf16x8;   // 8 bf16 = 4 VGPRs
typedef __attribute__((ext_vector_type(4))) float f32x4;    // MFMA accumulator

__device__ __forceinline__ unsigned short f2bf(float f) {
  unsigned int x = __float_as_uint(f);
  x += 0x7fffu + ((x >> 16) & 1u);       // round-to-nearest-even
  return (unsigned short)(x >> 16);
}
__device__ __forceinline__ float bf2f(unsigned short u) {
  return __uint_as_float(((unsigned int)u) << 16);
}

// raw workgroup barrier, NO vmcnt/lgkm drain; empty memory-clobber asm pins
// compiler-level ordering of LDS ops around it.
__device__ __forceinline__ void bar_sync() {
  asm volatile("" ::: "memory");
  __builtin_amdgcn_s_barrier();
  asm volatile("" ::: "memory");
}

// ---------------- fallback: ws too small -> zero out, report ws_size in aux ----------------
__global__ void fallback_kernel(float* out, int out_size, float wsval) {
  size_t i = (size_t)blockIdx.x * blockDim.x + threadIdx.x;
  size_t stride = (size_t)gridDim.x * blockDim.x;
  for (size_t k = i; k < (size_t)out_size; k += stride)
    out[k] = (k == (size_t)out_size - 1) ? wsval : 0.f;
}

// ---------------- zero control block ----------------
__global__ void zero_ctrl_kernel(float* imp, int* counts, int* order) {
  int i = threadIdx.x;
  if (i < E_NUM) { imp[i] = 0.f; counts[i] = 0; order[i] = 0; }
}

// ---- transpose + f32->bf16 convert: src [E][R][C] f32 -> dst [E][C][R] bf16 ----
__global__ __launch_bounds__(256) void transpose_kernel(
    const float* __restrict__ src, unsigned short* __restrict__ dst, int R, int C) {
  __shared__ float tile[32][33];
  int e = blockIdx.z;
  int c0 = blockIdx.x * 32, r0 = blockIdx.y * 32;
  int tx = threadIdx.x & 31, ty = threadIdx.x >> 5;
  const float* s = src + ((size_t)e * R + r0) * C + c0;
#pragma unroll
  for (int k = 0; k < 4; ++k) tile[ty + 8 * k][tx] = s[(size_t)(ty + 8 * k) * C + tx];
  __syncthreads();
  unsigned short* d = dst + ((size_t)e * C + c0) * R + r0;
#pragma unroll
  for (int k = 0; k < 4; ++k) d[(size_t)(ty + 8 * k) * R + tx] = f2bf(tile[tx][ty + 8 * k]);
}

// ---------------- router: fp64 logits/softmax/top-2 (tie-flip safety), importance/load ----------------
__global__ __launch_bounds__(256) void router_kernel(
    const float* __restrict__ x, const float* __restrict__ Wr,
    int* __restrict__ top_idx, float* __restrict__ top_w,
    float* __restrict__ importance, int* __restrict__ counts) {
  __shared__ float s_imp[E_NUM];
  __shared__ int s_cnt[E_NUM];
  int tid = threadIdx.x;
  if (tid < E_NUM) { s_imp[tid] = 0.f; s_cnt[tid] = 0; }
  __syncthreads();
  int wave = tid >> 6, lane = tid & 63;
  int t = blockIdx.x * 4 + wave;           // one wave per token
  double acc[E_NUM];
#pragma unroll
  for (int e = 0; e < E_NUM; ++e) acc[e] = 0.0;
  const float* xt = x + (size_t)t * H_DIM;
#pragma unroll 2
  for (int i = 0; i < H_DIM / 64; ++i) {
    int h = i * 64 + lane;
    double xv = (double)xt[h];
    const float4* wr = (const float4*)(Wr + h * E_NUM);
    float4 w0 = wr[0], w1 = wr[1];
    acc[0] += xv * (double)w0.x; acc[1] += xv * (double)w0.y;
    acc[2] += xv * (double)w0.z; acc[3] += xv * (double)w0.w;
    acc[4] += xv * (double)w1.x; acc[5] += xv * (double)w1.y;
    acc[6] += xv * (double)w1.z; acc[7] += xv * (double)w1.w;
  }
#pragma unroll
  for (int e = 0; e < E_NUM; ++e)
    for (int off = 32; off; off >>= 1) acc[e] += __shfl_xor(acc[e], off, 64);
  if (lane == 0) {
    double mx = acc[0];
#pragma unroll
    for (int e = 1; e < E_NUM; ++e) mx = acc[e] > mx ? acc[e] : mx;
    double p[E_NUM]; double s = 0.0;
#pragma unroll
    for (int e = 0; e < E_NUM; ++e) { p[e] = exp(acc[e] - mx); s += p[e]; }
    double inv = 1.0 / s;
    // top-2 (ties -> lower index, matching jax.lax.top_k)
    int i0 = 0; double p0 = p[0];
#pragma unroll
    for (int e = 1; e < E_NUM; ++e) if (p[e] > p0) { p0 = p[e]; i0 = e; }
    int i1 = -1; double p1 = -1.0;
#pragma unroll
    for (int e = 0; e < E_NUM; ++e) if (e != i0 && p[e] > p1) { p1 = p[e]; i1 = e; }
    double wsum = p0 + p1;
    top_idx[2 * t] = i0; top_idx[2 * t + 1] = i1;
    top_w[2 * t] = (float)(p0 / wsum);
    top_w[2 * t + 1] = (float)(p1 / wsum);
#pragma unroll
    for (int e = 0; e < E_NUM; ++e) atomicAdd(&s_imp[e], (float)(p[e] * inv));
    atomicAdd(&s_cnt[i0], 1); atomicAdd(&s_cnt[i1], 1);
  }
  __syncthreads();
  if (tid < E_NUM) { atomicAdd(&importance[tid], s_imp[tid]); atomicAdd(&counts[tid], s_cnt[tid]); }
}

// ---------------- aux loss ----------------
__global__ void aux_kernel(const float* __restrict__ importance, const int* __restrict__ counts,
                           float* __restrict__ aux_out) {
  if (threadIdx.x == 0) {
    float s = 0.f;
    for (int e = 0; e < E_NUM; ++e) s += importance[e] * (float)counts[e];
    *aux_out = (float)E_NUM * s / (float)N_SLOT;
  }
}

// ---------------- per-slot position assignment ----------------
__global__ __launch_bounds__(256) void assign_pos_kernel(
    const int* __restrict__ top_idx, const float* __restrict__ top_w,
    const int* __restrict__ counts, int* __restrict__ order, int* __restrict__ pos) {
  int i = blockIdx.x * 256 + threadIdx.x;
  if (i >= N_SLOT) return;
  int e = top_idx[i];
  int c = counts[e];
  if (c <= CAP) {
    pos[i] = atomicAdd(&order[e], 1);
  } else {
    float p = top_w[i]; int r = 0;
    for (int j = 0; j < N_SLOT; ++j) {
      if (top_idx[j] == e) {
        float q = top_w[j];
        r += (q > p) || (q == p && j < i);
      }
    }
    pos[i] = (r < CAP) ? r : -1;   // dropped
  }
}

// ---------------- dispatch: x[token] -> x_disp[e][pos] (bf16) ----------------
__global__ __launch_bounds__(256) void dispatch_kernel(
    const float* __restrict__ x, const int* __restrict__ top_idx,
    const int* __restrict__ pos, unsigned short* __restrict__ xd) {
  int s = blockIdx.x;
  int p = pos[s];
  if (p < 0) return;
  int e = top_idx[s];
  int t = s >> 1;
  float4 v = ((const float4*)(x + (size_t)t * H_DIM))[threadIdx.x];
  unsigned short* d = xd + ((size_t)e * CAP + p) * H_DIM + threadIdx.x * 4;
  *(ushort4*)d = make_ushort4(f2bf(v.x), f2bf(v.y), f2bf(v.z), f2bf(v.w));
}

// ---------------- GEMM staging: ROWSx32 bf16 tile via global_load_lds ----------------
// LDS row m chunk q (16B chunks, 4/row) holds global chunk q ^ ((m>>1)&3): breaks the
// 64B-row same-bank pattern for ds_read_b128 fragment reads (measured 0 conflicts).
// LDS dest linear (wave-uniform base + lane*16B contract); global SOURCE pre-swizzled.
template<int NCHUNK>
__device__ __forceinline__ void stage32(const unsigned short* __restrict__ g,
                                        unsigned short* s, int ldg, int tid) {
#pragma unroll
  for (int j = 0; j < NCHUNK / 512; ++j) {
    int c = j * 512 + tid;
    int m = c >> 2;
    int kc = (c & 3) ^ ((m >> 1) & 3);
    const unsigned short* gp = g + (size_t)m * ldg + kc * 8;
    __builtin_amdgcn_global_load_lds((const __attribute__((address_space(1))) void*)gp,
                                     (__attribute__((address_space(3))) void*)(s + (size_t)c * 8),
                                     16, 0, 0);
  }
}
// NCHUNK=512 case (B tiles of gateup): one load, no loop
__device__ __forceinline__ void stage32_512(const unsigned short* __restrict__ g,
                                            unsigned short* s, int ldg, int tid) {
  int m = tid >> 2;
  int kc = (tid & 3) ^ ((m >> 1) & 3);
  const unsigned short* gp = g + (size_t)m * ldg + kc * 8;
  __builtin_amdgcn_global_load_lds((const __attribute__((address_space(1))) void*)gp,
                                   (__attribute__((address_space(3))) void*)(s + (size_t)tid * 8),
                                   16, 0, 0);
}

// ---------------- fused gate/up GEMM + SiLU: h = silu(X@Wg) * (X@Wu) ----------------
// 256x128 tile, 8 waves (4M x 2N, per-wave 64x64 dual acc). BK=32 sub-tiles in a
// ring of 4 LDS buffers (128 KB), depth-3 prefetch. 8-phase-style schedule (T3+T4+T5):
// per sub-tile, exactly one counted vmcnt (8, tail-peeled 4/0), then two 16-MFMA
// phases, each {ds_read frags || issue a slice of sub-tile t+3's loads -> barrier ->
// lgkmcnt(0)+sched_barrier(0) -> setprio(1) MFMA setprio(0) -> barrier}.
__global__ __launch_bounds__(512, 2) void gateup_kernel(
    const unsigned short* __restrict__ xd, const unsigned short* __restrict__ wgT,
    const unsigned short* __restrict__ wuT, const int* __restrict__ counts,
    unsigned short* __restrict__ hbuf, int e0) {
  int ez = blockIdx.z;                    // local expert index within group
  int e = e0 + ez;                        // global expert
  int rows = counts[e]; rows = rows > CAP ? CAP : rows;
  int tm = blockIdx.y * 256;
  if (tm >= rows) return;                 // block-uniform early exit (before any barrier)
  int tn = blockIdx.x * 128;
  __shared__ __align__(16) unsigned short sA[4][256 * 32];   // 4 x 16 KB
  __shared__ __align__(16) unsigned short sBg[4][128 * 32];  // 4 x 8 KB
  __shared__ __align__(16) unsigned short sBu[4][128 * 32];  // 4 x 8 KB
  int tid = threadIdx.x;
  int lane = tid & 63, wave = tid >> 6;
  int quad = lane >> 4, lr = lane & 15;
  int wm = (wave >> 1) * 64, wn = (wave & 1) * 64;
  const unsigned short* A  = xd  + ((size_t)e * CAP + tm) * H_DIM;
  const unsigned short* Bg = wgT + ((size_t)e * F_DIM + tn) * H_DIM;
  const unsigned short* Bu = wuT + ((size_t)e * F_DIM + tn) * H_DIM;
  f32x4 accg[4][4], accu[4][4];
  f32x4 zero = {0.f, 0.f, 0.f, 0.f};
#pragma unroll
  for (int i = 0; i < 4; ++i)
#pragma unroll
    for (int j = 0; j < 4; ++j) { accg[i][j] = zero; accu[i][j] = zero; }

  // prologue: sub-tiles 0..2 in flight (12 loads/thread)
#pragma unroll
  for (int p = 0; p < 3; ++p) {
    stage32<1024>(A + p * 32, sA[p], H_DIM, tid);
    stage32_512(Bg + p * 32, sBg[p], H_DIM, tid);
    stage32_512(Bu + p * 32, sBu[p], H_DIM, tid);
  }
  const int NT = H_DIM / 32;  // 32
  for (int t = 0; t < NT; ++t) {
    // counted wait: sub-tile t's 4 loads landed; t+1..t+3 stay in flight (uniform branch)
    if (t < NT - 2)      asm volatile("s_waitcnt vmcnt(8)" ::: "memory");
    else if (t == NT - 2) asm volatile("s_waitcnt vmcnt(4)" ::: "memory");
    else                  asm volatile("s_waitcnt vmcnt(0)" ::: "memory");
    bar_sync();                       // buf[t&3] valid on all waves; seals reads of t-1
    const unsigned short* a  = sA[t & 3];
    const unsigned short* bg = sBg[t & 3];
    const unsigned short* bu = sBu[t & 3];
    bf16x8 af[4], gf[4], uf[4];
    // ---- phase g: ds_read A+Bg frags, prefetch slice (A + Bg of t+3), 16 MFMA ----
#pragma unroll
    for (int i = 0; i < 4; ++i) {
      int m = wm + i * 16 + lr;
      af[i] = *(const bf16x8*)&a[m * 32 + ((quad ^ ((m >> 1) & 3)) << 3)];
    }
#pragma unroll
    for (int j = 0; j < 4; ++j) {
      int n = wn + j * 16 + lr;
      gf[j] = *(const bf16x8*)&bg[n * 32 + ((quad ^ ((n >> 1) & 3)) << 3)];
    }
    if (t + 3 < NT) {
      stage32<1024>(A + (t + 3) * 32, sA[(t + 3) & 3], H_DIM, tid);
      stage32_512(Bg + (t + 3) * 32, sBg[(t + 3) & 3], H_DIM, tid);
    }
    bar_sync();
    asm volatile("s_waitcnt lgkmcnt(0)" ::: "memory");
    __builtin_amdgcn_sched_barrier(0);
    __builtin_amdgcn_s_setprio(1);
#pragma unroll
    for (int i = 0; i < 4; ++i)
#pragma unroll
      for (int j = 0; j < 4; ++j)
        accg[i][j] = __builtin_amdgcn_mfma_f32_16x16x32_bf16(af[i], gf[j], accg[i][j], 0, 0, 0);
    __builtin_amdgcn_s_setprio(0);
    bar_sync();
    // ---- phase u: ds_read Bu frags (af reused from regs), prefetch Bu of t+3, 16 MFMA ----
#pragma unroll
    for (int j = 0; j < 4; ++j) {
      int n = wn + j * 16 + lr;
      uf[j] = *(const bf16x8*)&bu[n * 32 + ((quad ^ ((n >> 1) & 3)) << 3)];
    }
    if (t + 3 < NT)
      stage32_512(Bu + (t + 3) * 32, sBu[(t + 3) & 3], H_DIM, tid);
    bar_sync();
    asm volatile("s_waitcnt lgkmcnt(0)" ::: "memory");
    __builtin_amdgcn_sched_barrier(0);
    __builtin_amdgcn_s_setprio(1);
#pragma unroll
    for (int i = 0; i < 4; ++i)
#pragma unroll
      for (int j = 0; j < 4; ++j)
        accu[i][j] = __builtin_amdgcn_mfma_f32_16x16x32_bf16(af[i], uf[j], accu[i][j], 0, 0, 0);
    __builtin_amdgcn_s_setprio(0);
  }

  // epilogue: silu(g)*u -> bf16  (C/D layout: row = quad*4+r, col = lr)
  unsigned short* hp = hbuf + ((size_t)ez * CAP + tm) * F_DIM + tn;
#pragma unroll
  for (int i = 0; i < 4; ++i)
#pragma unroll
    for (int j = 0; j < 4; ++j)
#pragma unroll
      for (int r = 0; r < 4; ++r) {
        int m = wm + i * 16 + quad * 4 + r;
        int n = wn + j * 16 + lr;
        float g = accg[i][j][r], u = accu[i][j][r];
        float hv = (g / (1.f + __expf(-g))) * u;
        hp[(size_t)m * F_DIM + n] = f2bf(hv);
      }
}

// ---------------- down GEMM: y = h @ W2 ----------------
// 256x256 tile, 8 waves (2M x 4N, per-wave 128x64). Same BK=32 ring-4 8-phase-style
// schedule; phase0 = i0..3 (A frags half + all B frags), phase1 = i4..7 (B reused).
__global__ __launch_bounds__(512, 2) void down_kernel(
    const unsigned short* __restrict__ hbuf, const unsigned short* __restrict__ w2T,
    const int* __restrict__ counts, unsigned short* __restrict__ ybuf, int e0) {
  int ez = blockIdx.z;
  int e = e0 + ez;
  int rows = counts[e]; rows = rows > CAP ? CAP : rows;
  int tm = blockIdx.y * 256;
  if (tm >= rows) return;
  int tn = blockIdx.x * 256;
  __shared__ __align__(16) unsigned short sA[4][256 * 32];   // 4 x 16 KB
  __shared__ __align__(16) unsigned short sB[4][256 * 32];   // 4 x 16 KB
  int tid = threadIdx.x;
  int lane = tid & 63, wave = tid >> 6;
  int quad = lane >> 4, lr = lane & 15;
  int wm = (wave >> 2) * 128, wn = (wave & 3) * 64;
  const unsigned short* A = hbuf + ((size_t)ez * CAP + tm) * F_DIM;
  const unsigned short* B = w2T + ((size_t)e * H_DIM + tn) * F_DIM;
  f32x4 acc[8][4];
  f32x4 zero = {0.f, 0.f, 0.f, 0.f};
#pragma unroll
  for (int i = 0; i < 8; ++i)
#pragma unroll
    for (int j = 0; j < 4; ++j) acc[i][j] = zero;

#pragma unroll
  for (int p = 0; p < 3; ++p) {
    stage32<1024>(A + p * 32, sA[p], F_DIM, tid);
    stage32<1024>(B + p * 32, sB[p], F_DIM, tid);
  }
  const int NT = F_DIM / 32;  // 64
  for (int t = 0; t < NT; ++t) {
    if (t < NT - 2)      asm volatile("s_waitcnt vmcnt(8)" ::: "memory");
    else if (t == NT - 2) asm volatile("s_waitcnt vmcnt(4)" ::: "memory");
    else                  asm volatile("s_waitcnt vmcnt(0)" ::: "memory");
    bar_sync();
    const unsigned short* a = sA[t & 3];
    const unsigned short* b = sB[t & 3];
    bf16x8 af[8], bf[4];
    // ---- phase 0: A frags i0..3 + all B frags, prefetch A slice of t+3, 16 MFMA ----
#pragma unroll
    for (int i = 0; i < 4; ++i) {
      int m = wm + i * 16 + lr;
      af[i] = *(const bf16x8*)&a[m * 32 + ((quad ^ ((m >> 1) & 3)) << 3)];
    }
#pragma unroll
    for (int j = 0; j < 4; ++j) {
      int n = wn + j * 16 + lr;
      bf[j] = *(const bf16x8*)&b[n * 32 + ((quad ^ ((n >> 1) & 3)) << 3)];
    }
    if (t + 3 < NT)
      stage32<1024>(A + (t + 3) * 32, sA[(t + 3) & 3], F_DIM, tid);
    bar_sync();
    asm volatile("s_waitcnt lgkmcnt(0)" ::: "memory");
    __builtin_amdgcn_sched_barrier(0);
    __builtin_amdgcn_s_setprio(1);
#pragma unroll
    for (int i = 0; i < 4; ++i)
#pragma unroll
      for (int j = 0; j < 4; ++j)
        acc[i][j] = __builtin_amdgcn_mfma_f32_16x16x32_bf16(af[i], bf[j], acc[i][j], 0, 0, 0);
    __builtin_amdgcn_s_setprio(0);
    bar_sync();
    // ---- phase 1: A frags i4..7 (B reused from regs), prefetch B slice of t+3, 16 MFMA ----
#pragma unroll
    for (int i = 4; i < 8; ++i) {
      int m = wm + i * 16 + lr;
      af[i] = *(const bf16x8*)&a[m * 32 + ((quad ^ ((m >> 1) & 3)) << 3)];
    }
    if (t + 3 < NT)
      stage32<1024>(B + (t + 3) * 32, sB[(t + 3) & 3], F_DIM, tid);
    bar_sync();
    asm volatile("s_waitcnt lgkmcnt(0)" ::: "memory");
    __builtin_amdgcn_sched_barrier(0);
    __builtin_amdgcn_s_setprio(1);
#pragma unroll
    for (int i = 4; i < 8; ++i)
#pragma unroll
      for (int j = 0; j < 4; ++j)
        acc[i][j] = __builtin_amdgcn_mfma_f32_16x16x32_bf16(af[i], bf[j], acc[i][j], 0, 0, 0);
    __builtin_amdgcn_s_setprio(0);
  }

  unsigned short* yp = ybuf + ((size_t)e * CAP + tm) * H_DIM + tn;
#pragma unroll
  for (int i = 0; i < 8; ++i)
#pragma unroll
    for (int j = 0; j < 4; ++j)
#pragma unroll
      for (int r = 0; r < 4; ++r) {
        int m = wm + i * 16 + quad * 4 + r;
        int n = wn + j * 16 + lr;
        yp[(size_t)m * H_DIM + n] = f2bf(acc[i][j][r]);
      }
}

// ---------------- combine: out[t] = sum_k w_k * y[e_k][pos_k] ----------------
__global__ __launch_bounds__(256) void combine_kernel(
    const unsigned short* __restrict__ ybuf, const int* __restrict__ top_idx,
    const int* __restrict__ pos, const float* __restrict__ top_w,
    float* __restrict__ out) {
  int t = blockIdx.x;
  int i0 = 2 * t, i1 = 2 * t + 1;
  int e0 = top_idx[i0], e1 = top_idx[i1];
  int p0 = pos[i0], p1 = pos[i1];
  float w0 = (p0 >= 0) ? top_w[i0] : 0.f;
  float w1 = (p1 >= 0) ? top_w[i1] : 0.f;
  size_t o0 = ((size_t)e0 * CAP + (p0 < 0 ? 0 : p0)) * H_DIM + threadIdx.x * 4;
  size_t o1 = ((size_t)e1 * CAP + (p1 < 0 ? 0 : p1)) * H_DIM + threadIdx.x * 4;
  ushort4 a = *(const ushort4*)(ybuf + o0);
  ushort4 b = *(const ushort4*)(ybuf + o1);
  float4 o;
  o.x = w0 * bf2f(a.x) + w1 * bf2f(b.x);
  o.y = w0 * bf2f(a.y) + w1 * bf2f(b.y);
  o.z = w0 * bf2f(a.z) + w1 * bf2f(b.z);
  o.w = w0 * bf2f(a.w) + w1 * bf2f(b.w);
  *(float4*)(out + (size_t)t * H_DIM + threadIdx.x * 4) = o;
}

extern "C" void kernel_launch(void* const* d_in, const int* in_sizes, int n_in,
                              void* d_out, int out_size, void* d_ws, size_t ws_size,
                              hipStream_t stream) {
  const float* x  = (const float*)d_in[0];   // [2,8192,1024]
  const float* Wr = (const float*)d_in[1];   // [1024,8]
  const float* Wg = (const float*)d_in[2];   // [8,1024,2048]
  const float* Wu = (const float*)d_in[3];   // [8,1024,2048]
  const float* W2 = (const float*)d_in[4];   // [8,2048,1024]
  float* out = (float*)d_out;                // [16M out] + [1 aux]

  // ---- workspace layout (grouped hbuf; peak 248.0 MB, ws_size = 256 MiB) ----
  const size_t SZ_W  = (size_t)E_NUM * F_DIM * H_DIM * 2;    // 33.55 MB per transposed weight
  const size_t SZ_XD = (size_t)E_NUM * CAP * H_DIM * 2;      // 83.89 MB
  const size_t SZ_HG = (size_t)EGROUP * CAP * F_DIM * 2;     // 62.91 MB (3-expert hbuf)
  const size_t NEED  = 524288 + 3 * SZ_W + SZ_XD + SZ_HG;    // 247.99 MB

  if (ws_size < NEED) {
    fallback_kernel<<<4096, 256, 0, stream>>>(out, out_size, (float)ws_size);
    return;
  }

  char* w = (char*)d_ws;
  float* importance = (float*)(w + 0);
  int* counts       = (int*)(w + 64);
  int* order        = (int*)(w + 128);
  int* top_idx      = (int*)(w + 1024);
  int* pos          = (int*)(w + 1024 + 131072);
  float* top_w      = (float*)(w + 1024 + 2 * 131072);
  size_t off = 524288;
  unsigned short* wgT  = (unsigned short*)(w + off); off += SZ_W;
  unsigned short* wuT  = (unsigned short*)(w + off); off += SZ_W;
  unsigned short* w2T  = (unsigned short*)(w + off); off += SZ_W;
  unsigned short* xd   = (unsigned short*)(w + off); off += SZ_XD;
  unsigned short* hbuf = (unsigned short*)(w + off); off += SZ_HG;
  unsigned short* ybuf = xd;    // aliases xd: down(e) runs after gateup(e) consumed xd[e]

  zero_ctrl_kernel<<<1, 64, 0, stream>>>(importance, counts, order);
  // weight transposes (src [E][R][C] f32 -> dst [E][C][R] bf16)
  transpose_kernel<<<dim3(F_DIM / 32, H_DIM / 32, E_NUM), 256, 0, stream>>>(Wg, wgT, H_DIM, F_DIM);
  transpose_kernel<<<dim3(F_DIM / 32, H_DIM / 32, E_NUM), 256, 0, stream>>>(Wu, wuT, H_DIM, F_DIM);
  transpose_kernel<<<dim3(H_DIM / 32, F_DIM / 32, E_NUM), 256, 0, stream>>>(W2, w2T, F_DIM, H_DIM);
  router_kernel<<<T_TOK / 4, 256, 0, stream>>>(x, Wr, top_idx, top_w, importance, counts);
  aux_kernel<<<1, 64, 0, stream>>>(importance, counts, out + (out_size - 1));
  assign_pos_kernel<<<N_SLOT / 256, 256, 0, stream>>>(top_idx, top_w, counts, order, pos);
  dispatch_kernel<<<N_SLOT, 256, 0, stream>>>(x, top_idx, pos, xd);
  // expert groups: hbuf holds <= EGROUP experts at a time
  for (int e0 = 0; e0 < E_NUM; e0 += EGROUP) {
    int ne = (E_NUM - e0) < EGROUP ? (E_NUM - e0) : EGROUP;
    gateup_kernel<<<dim3(F_DIM / 128, CAP / 256, ne), 512, 0, stream>>>(xd, wgT, wuT, counts, hbuf, e0);
    down_kernel<<<dim3(H_DIM / 256, CAP / 256, ne), 512, 0, stream>>>(hbuf, w2T, counts, ybuf, e0);
  }
  combine_kernel<<<T_TOK, 256, 0, stream>>>(ybuf, top_idx, pos, top_w, out);
}